// Round 8
// baseline (2318.027 us; speedup 1.0000x reference)
//
#include <hip/hip_runtime.h>
#include <hip/hip_bf16.h>

#define B_ 32
#define S_ 64
#define H_ 512
#define V_ 32000
#define T_ 64
#define SENT_ 0xFFC00000u

typedef __bf16 bf16x8 __attribute__((ext_vector_type(8)));
typedef float f32x4 __attribute__((ext_vector_type(4)));

__device__ __forceinline__ float fast_tanh(float x) {
  float e = __expf(2.0f * x);
  return 1.0f - 2.0f / (e + 1.0f);
}
__device__ __forceinline__ float fast_sigmoid(float x) {
  return 1.0f / (1.0f + __expf(-x));
}
__device__ __forceinline__ unsigned ld_agent(const unsigned* p) {
  return __hip_atomic_load(p, __ATOMIC_RELAXED, __HIP_MEMORY_SCOPE_AGENT);
}
__device__ __forceinline__ void st_agent(float* p, float v) {
  __hip_atomic_store(p, v, __ATOMIC_RELAXED, __HIP_MEMORY_SCOPE_AGENT);
}

// ---------------- prep kernels ----------------

__global__ __launch_bounds__(256) void k_emb_gather(const int* __restrict__ target,
    const float* __restrict__ emb, __hip_bfloat16* __restrict__ emb_bf) {
  int row = blockIdx.x;                 // t*32 + b
  int t = row >> 5, b = row & 31;
  int tok = (t == 0) ? 0 : target[b * T_ + t - 1];
  const float* src = emb + (size_t)tok * H_;
  __hip_bfloat16* dst = emb_bf + (size_t)row * H_;
  for (int jj = threadIdx.x; jj < H_; jj += 256) dst[jj] = __float2bfloat16(src[jj]);
}

__global__ __launch_bounds__(256) void k_cvt_dense(const float* __restrict__ src,
    __hip_bfloat16* __restrict__ dst, int n4) {
  int i = blockIdx.x * 256 + threadIdx.x;
  if (i < n4) {
    const float4 v = ((const float4*)src)[i];
    union { __hip_bfloat16 h[4]; uint2 u; } cv;
    cv.h[0] = __float2bfloat16(v.x); cv.h[1] = __float2bfloat16(v.y);
    cv.h[2] = __float2bfloat16(v.z); cv.h[3] = __float2bfloat16(v.w);
    *(uint2*)(dst + (size_t)i * 4) = cv.u;
  }
}

// W_ihc (= W_ih[:, 512:1024]) -> packed bf16 [1536][512]
__global__ __launch_bounds__(128) void k_cvt_wihc(const float* __restrict__ W_ih,
    __hip_bfloat16* __restrict__ dst) {
  const int row = blockIdx.x;           // 0..1535
  const int c4 = threadIdx.x * 4;
  const float4 v = *(const float4*)(W_ih + (size_t)row * 1024 + 512 + c4);
  union { __hip_bfloat16 h[4]; uint2 u; } cv;
  cv.h[0] = __float2bfloat16(v.x); cv.h[1] = __float2bfloat16(v.y);
  cv.h[2] = __float2bfloat16(v.z); cv.h[3] = __float2bfloat16(v.w);
  *(uint2*)(dst + (size_t)row * 512 + c4) = cv.u;
}

// Wq (rows 0..511) and W_hh (rows 512..2047) -> bf16
__global__ __launch_bounds__(256) void k_cvt_wqh(const float* __restrict__ Wq,
    const float* __restrict__ W_hh, __hip_bfloat16* __restrict__ wq_bf,
    __hip_bfloat16* __restrict__ whh_bf) {
  const int row = blockIdx.x;           // 0..2047
  const int c2 = threadIdx.x * 2;
  const float* src = (row < 512) ? (Wq + (size_t)row * 512)
                                 : (W_hh + (size_t)(row - 512) * 512);
  __hip_bfloat16* dst = (row < 512) ? (wq_bf + (size_t)row * 512)
                                    : (whh_bf + (size_t)(row - 512) * 512);
  const float2 v = *(const float2*)(src + c2);
  union { __hip_bfloat16 h[2]; unsigned u; } cv;
  cv.h[0] = __float2bfloat16(v.x); cv.h[1] = __float2bfloat16(v.y);
  *(unsigned*)(dst + c2) = cv.u;
}

// fill h_st[1..64] + partial_st with the sentinel pattern (one contiguous range)
__global__ __launch_bounds__(256) void k_clear(uint4* __restrict__ dst) {
  const uint4 s4 = {SENT_, SENT_, SENT_, SENT_};
  dst[(size_t)blockIdx.x * 256 + threadIdx.x] = s4;
}

__global__ __launch_bounds__(256) void k_init(const float* __restrict__ ehs,
    float* __restrict__ h_st0) {
  int i = blockIdx.x * 256 + threadIdx.x;
  if (i < B_ * H_) h_st0[i] = ehs[i];
}

// ---------------- generic bf16-MFMA GEMM: C[M,N] = A[M,K] @ B[N,K]^T (+bias) ----------------

__global__ __launch_bounds__(256) void k_gemm_bf16(
    const __hip_bfloat16* __restrict__ A, int lda,
    const float* __restrict__ B, int ldb,
    const float* __restrict__ bias,
    float* __restrict__ C, int ldc, int K) {
  __shared__ float pool[128 * 68];
  __hip_bfloat16* Asub = (__hip_bfloat16*)pool;
  __hip_bfloat16* Bsub = (__hip_bfloat16*)(pool + 2048);
  const int tid = threadIdx.x;
  const int lane = tid & 63, wave = tid >> 6;
  const int wr = wave >> 1, wc = wave & 1;
  const int n0 = blockIdx.x * 128, m0 = blockIdx.y * 128;
  f32x4 acc[4][4];
#pragma unroll
  for (int i = 0; i < 4; ++i)
#pragma unroll
    for (int jj = 0; jj < 4; ++jj) acc[i][jj] = (f32x4){0.f, 0.f, 0.f, 0.f};

  for (int k0 = 0; k0 < K; k0 += 32) {
    uint4 a_v[2];
#pragma unroll
    for (int rr = 0; rr < 2; ++rr) {
      const int seg = tid + rr * 256;
      const int row = seg >> 2, ks8 = (seg & 3) * 8;
      a_v[rr] = *(const uint4*)(A + (size_t)(m0 + row) * lda + k0 + ks8);
    }
    float4 b_v[4];
#pragma unroll
    for (int rr = 0; rr < 4; ++rr) {
      const int idx = tid + rr * 256;
      const int n = idx >> 3, kg = (idx & 7) * 4;
      b_v[rr] = *(const float4*)(B + (size_t)(n0 + n) * ldb + k0 + kg);
    }
    __syncthreads();
#pragma unroll
    for (int rr = 0; rr < 2; ++rr) {
      const int seg = tid + rr * 256;
      *(uint4*)(Asub + seg * 8) = a_v[rr];
    }
#pragma unroll
    for (int rr = 0; rr < 4; ++rr) {
      const int idx = tid + rr * 256;
      const int n = idx >> 3, kg = (idx & 7) * 4;
      union { __hip_bfloat16 h[4]; uint2 u; } cv;
      cv.h[0] = __float2bfloat16(b_v[rr].x);
      cv.h[1] = __float2bfloat16(b_v[rr].y);
      cv.h[2] = __float2bfloat16(b_v[rr].z);
      cv.h[3] = __float2bfloat16(b_v[rr].w);
      *(uint2*)(Bsub + n * 32 + kg) = cv.u;
    }
    __syncthreads();
    bf16x8 af[4], bfr[4];
#pragma unroll
    for (int mi = 0; mi < 4; ++mi)
      af[mi] = *(const bf16x8*)(Asub + (wr * 64 + mi * 16 + (lane & 15)) * 32 + (lane >> 4) * 8);
#pragma unroll
    for (int ni = 0; ni < 4; ++ni)
      bfr[ni] = *(const bf16x8*)(Bsub + (wc * 64 + ni * 16 + (lane & 15)) * 32 + (lane >> 4) * 8);
#pragma unroll
    for (int mi = 0; mi < 4; ++mi)
#pragma unroll
      for (int ni = 0; ni < 4; ++ni)
        acc[mi][ni] = __builtin_amdgcn_mfma_f32_16x16x32_bf16(af[mi], bfr[ni], acc[mi][ni], 0, 0, 0);
  }

  float* Cs = pool;
  const int r4 = (lane >> 4) * 4, cc = lane & 15;
#pragma unroll
  for (int hf = 0; hf < 2; ++hf) {
    __syncthreads();
    if (wc == hf) {
#pragma unroll
      for (int ni = 0; ni < 4; ++ni) {
        const float bb = bias ? bias[n0 + hf * 64 + ni * 16 + cc] : 0.f;
#pragma unroll
        for (int mi = 0; mi < 4; ++mi)
#pragma unroll
          for (int i = 0; i < 4; ++i)
            Cs[(wr * 64 + mi * 16 + r4 + i) * 68 + ni * 16 + cc] = acc[mi][ni][i] + bb;
      }
    }
    __syncthreads();
    const int rowp = tid >> 4, colg = tid & 15;
#pragma unroll
    for (int pass = 0; pass < 8; ++pass) {
      const int row = pass * 16 + rowp;
      const float4 v = *(const float4*)(Cs + row * 68 + colg * 4);
      *(float4*)(C + (size_t)(m0 + row) * ldc + n0 + hf * 64 + colg * 4) = v;
    }
  }
}

// ---------------- recurrence: 32 independent 8-block clusters, sentinel dataflow ----------------
// block = b*8 + j (XCD = j). Producers: fire-and-forget relaxed agent stores.
// Consumers: poll the payload dwords themselves (NaN sentinel), consume from regs.

__global__ __launch_bounds__(256) void k_recur(
    const __hip_bfloat16* __restrict__ wq_bf, const __hip_bfloat16* __restrict__ whh_bf,
    const float* __restrict__ bq,
    const float* __restrict__ kproj,
    const float* __restrict__ Wv, const float* __restrict__ bv,
    const float* __restrict__ encprojT, const float* __restrict__ giemb,
    const float* __restrict__ b_hh,
    float* h_st, float* partial_st,
    float* __restrict__ attn_out, __hip_bfloat16* __restrict__ Hall,
    float* __restrict__ hfin) {
  const int tid = threadIdx.x;
  const int b = blockIdx.x >> 3, j = blockIdx.x & 7;
  const int r8 = tid >> 3, kc = tid & 7;   // GEMV: 32 rows x 8 k-chunks of 64

  __shared__ float h_s[8 * 68];         // padded: idx = (i>>6)*68 + (i&63)
  __shared__ float q_s[64];
  __shared__ float gh_s[192];
  __shared__ float w_s[64];
  __shared__ float gic_s[192];

  float4 hreg[16];

  for (int t = 0; t < T_; ++t) {
    // ---- poll h_st[t] (512 dwords, 2 per thread) ----
    {
      const unsigned* hsrc = (const unsigned*)(h_st + (size_t)t * (B_ * H_) + b * H_);
      unsigned hv0 = ld_agent(hsrc + tid);
      unsigned hv1 = ld_agent(hsrc + 256 + tid);
      for (;;) {
        const bool bad = (hv0 == SENT_) || (hv1 == SENT_);
        if (!__any(bad)) break;
        __builtin_amdgcn_s_sleep(1);
        if (hv0 == SENT_) hv0 = ld_agent(hsrc + tid);
        if (hv1 == SENT_) hv1 = ld_agent(hsrc + 256 + tid);
      }
      h_s[(tid >> 6) * 68 + (tid & 63)] = __uint_as_float(hv0);
      h_s[((tid >> 6) + 4) * 68 + (tid & 63)] = __uint_as_float(hv1);
    }
    __syncthreads();
#pragma unroll
    for (int i = 0; i < 16; ++i)
      hreg[i] = *(const float4*)(h_s + kc * 68 + i * 4);

    // bf16 GEMV helper: dot(wrow[kc*64 .. +64), h) reduced over kc lanes
    auto dotw = [&](const __hip_bfloat16* wrow) -> float {
      const uint4* w8 = (const uint4*)wrow;
      float p = 0.f;
#pragma unroll
      for (int i = 0; i < 8; ++i) {
        const uint4 w = w8[kc * 8 + i];
        const float4 ha = hreg[2 * i], hb = hreg[2 * i + 1];
        p += __uint_as_float(w.x << 16) * ha.x + __uint_as_float(w.x & 0xffff0000u) * ha.y;
        p += __uint_as_float(w.y << 16) * ha.z + __uint_as_float(w.y & 0xffff0000u) * ha.w;
        p += __uint_as_float(w.z << 16) * hb.x + __uint_as_float(w.z & 0xffff0000u) * hb.y;
        p += __uint_as_float(w.w << 16) * hb.z + __uint_as_float(w.w & 0xffff0000u) * hb.w;
      }
      p += __shfl_xor(p, 1); p += __shfl_xor(p, 2); p += __shfl_xor(p, 4);
      return p;
    };

    // ---- q slice: rows j*64 .. j*64+64 of Wq ----
#pragma unroll
    for (int it = 0; it < 2; ++it) {
      const int row = j * 64 + it * 32 + r8;
      const float p = dotw(wq_bf + (size_t)row * H_);
      if (kc == 0) q_s[it * 32 + r8] = p + bq[row];
    }
    __syncthreads();

    // ---- partial scores over this block's 64 h-dims ----
    {
      const int s = tid >> 2, q4 = tid & 3;
      const float4* kp = (const float4*)(kproj + ((size_t)(b * S_ + s)) * H_ + j * 64 + q4 * 16);
      const float4* qp = (const float4*)(q_s + q4 * 16);
      const float4* wv = (const float4*)(Wv + j * 64 + q4 * 16);
      float sc = 0.f;
#pragma unroll
      for (int i = 0; i < 4; ++i) {
        const float4 k4 = kp[i], qq = qp[i], vv = wv[i];
        sc += vv.x * fast_tanh(qq.x + k4.x) + vv.y * fast_tanh(qq.y + k4.y)
            + vv.z * fast_tanh(qq.z + k4.z) + vv.w * fast_tanh(qq.w + k4.w);
      }
      sc += __shfl_xor(sc, 1); sc += __shfl_xor(sc, 2);
      if (q4 == 0)
        st_agent(&partial_st[(((size_t)t * B_ + b) * 8 + j) * 64 + s], sc);  // fire & forget
    }

    // ---- gh slices (overlaps partial flight) ----
#pragma unroll
    for (int g = 0; g < 3; ++g)
#pragma unroll
      for (int it = 0; it < 2; ++it) {
        const int row = g * H_ + j * 64 + it * 32 + r8;
        const float p = dotw(whh_bf + (size_t)row * H_);
        if (kc == 0) gh_s[g * 64 + it * 32 + r8] = p;
      }

    // ---- gather partials (poll payload) + softmax (redundant per block) ----
    if (tid < 64) {
      const unsigned* pb = (const unsigned*)(partial_st + ((size_t)t * B_ + b) * 512);
      unsigned pv[8];
#pragma unroll
      for (int jj = 0; jj < 8; ++jj) pv[jj] = ld_agent(pb + jj * 64 + tid);
      for (;;) {
        bool bad = false;
#pragma unroll
        for (int jj = 0; jj < 8; ++jj) bad |= (pv[jj] == SENT_);
        if (!__any(bad)) break;
        __builtin_amdgcn_s_sleep(1);
#pragma unroll
        for (int jj = 0; jj < 8; ++jj)
          if (pv[jj] == SENT_) pv[jj] = ld_agent(pb + jj * 64 + tid);
      }
      float sc = bv[0];
#pragma unroll
      for (int jj = 0; jj < 8; ++jj) sc += __uint_as_float(pv[jj]);
      float m = sc;
#pragma unroll
      for (int d = 32; d > 0; d >>= 1) m = fmaxf(m, __shfl_xor(m, d));
      const float e = __expf(sc - m);
      float sum = e;
#pragma unroll
      for (int d = 32; d > 0; d >>= 1) sum += __shfl_xor(sum, d);
      const float w = e / sum;
      w_s[tid] = w;
      if (j == (b & 7)) attn_out[((size_t)b * T_ + t) * S_ + tid] = w;
    }
    __syncthreads();

    // ---- gic slices: gic[row] = sum_s w[s] * encprojT[row][b*64+s] ----
    if (tid < 192) {
      const int g = tid >> 6, dd = tid & 63;
      const int grow = g * H_ + j * 64 + dd;
      const float4* ep = (const float4*)(encprojT + (size_t)grow * 2048 + b * 64);
      const float4* wp = (const float4*)w_s;
      float a = 0.f;
#pragma unroll
      for (int i = 0; i < 16; ++i) {
        const float4 e4 = ep[i], w4 = wp[i];
        a += e4.x * w4.x + e4.y * w4.y + e4.z * w4.z + e4.w * w4.w;
      }
      gic_s[tid] = a;
    }
    __syncthreads();

    // ---- gates for h-dims [j*64,(j+1)*64) ----
    if (tid < 64) {
      const int hh = j * 64 + tid;
      const size_t grow = ((size_t)t * B_ + b) * 1536;
      const float ir  = giemb[grow + hh]        + gic_s[tid];
      const float iz  = giemb[grow + 512 + hh]  + gic_s[64 + tid];
      const float in_ = giemb[grow + 1024 + hh] + gic_s[128 + tid];
      const float hr  = gh_s[tid]        + b_hh[hh];
      const float hz  = gh_s[64 + tid]   + b_hh[512 + hh];
      const float hn  = gh_s[128 + tid]  + b_hh[1024 + hh];
      const float rg = fast_sigmoid(ir + hr);
      const float zg = fast_sigmoid(iz + hz);
      const float ng = fast_tanh(in_ + rg * hn);
      const float ho = h_s[j * 68 + tid];
      const float hv = (1.f - zg) * ng + zg * ho;
      st_agent(&h_st[(size_t)(t + 1) * (B_ * H_) + b * H_ + hh], hv);  // fire & forget
      Hall[((size_t)b * T_ + t) * H_ + hh] = __float2bfloat16(hv);
      if (t == T_ - 1) hfin[b * H_ + hh] = hv;
    }
    __syncthreads();
  }
}

// ---------------- logits GEMM (XCD-chunked n-tiles) ----------------

__global__ __launch_bounds__(256) void k_logits(
    const __hip_bfloat16* __restrict__ Hall, const float* __restrict__ Wo,
    const float* __restrict__ bo, float* __restrict__ out0) {
  __shared__ float pool[128 * 68];
  __hip_bfloat16* Asub = (__hip_bfloat16*)pool;
  __hip_bfloat16* Bsub = (__hip_bfloat16*)(pool + 2048);
  const int tid = threadIdx.x;
  const int lane = tid & 63, wave = tid >> 6;
  const int wr = wave >> 1, wc = wave & 1;
  const int flat = blockIdx.x;                  // 0..3999
  const int nf = (flat & 7) * 500 + (flat >> 3);
  const int m0 = (nf & 15) * 128, n0 = (nf >> 4) * 128;
  f32x4 acc[4][4];
#pragma unroll
  for (int i = 0; i < 4; ++i)
#pragma unroll
    for (int jj = 0; jj < 4; ++jj) acc[i][jj] = (f32x4){0.f, 0.f, 0.f, 0.f};

  for (int k0 = 0; k0 < 512; k0 += 32) {
    uint4 a_v[2];
#pragma unroll
    for (int rr = 0; rr < 2; ++rr) {
      const int seg = tid + rr * 256;
      const int row = seg >> 2, ks8 = (seg & 3) * 8;
      a_v[rr] = *(const uint4*)(Hall + (size_t)(m0 + row) * 512 + k0 + ks8);
    }
    float4 b_v[4];
#pragma unroll
    for (int rr = 0; rr < 4; ++rr) {
      const int idx = tid + rr * 256;
      const int n = idx >> 3, kg = (idx & 7) * 4;
      b_v[rr] = *(const float4*)(Wo + (size_t)(n0 + n) * 512 + k0 + kg);
    }
    __syncthreads();
#pragma unroll
    for (int rr = 0; rr < 2; ++rr) {
      const int seg = tid + rr * 256;
      *(uint4*)(Asub + seg * 8) = a_v[rr];
    }
#pragma unroll
    for (int rr = 0; rr < 4; ++rr) {
      const int idx = tid + rr * 256;
      const int n = idx >> 3, kg = (idx & 7) * 4;
      union { __hip_bfloat16 h[4]; uint2 u; } cv;
      cv.h[0] = __float2bfloat16(b_v[rr].x);
      cv.h[1] = __float2bfloat16(b_v[rr].y);
      cv.h[2] = __float2bfloat16(b_v[rr].z);
      cv.h[3] = __float2bfloat16(b_v[rr].w);
      *(uint2*)(Bsub + n * 32 + kg) = cv.u;
    }
    __syncthreads();
    bf16x8 af[4], bfr[4];
#pragma unroll
    for (int mi = 0; mi < 4; ++mi)
      af[mi] = *(const bf16x8*)(Asub + (wr * 64 + mi * 16 + (lane & 15)) * 32 + (lane >> 4) * 8);
#pragma unroll
    for (int ni = 0; ni < 4; ++ni)
      bfr[ni] = *(const bf16x8*)(Bsub + (wc * 64 + ni * 16 + (lane & 15)) * 32 + (lane >> 4) * 8);
#pragma unroll
    for (int mi = 0; mi < 4; ++mi)
#pragma unroll
      for (int ni = 0; ni < 4; ++ni)
        acc[mi][ni] = __builtin_amdgcn_mfma_f32_16x16x32_bf16(af[mi], bfr[ni], acc[mi][ni], 0, 0, 0);
  }

  float* Cs = pool;
  const int r4 = (lane >> 4) * 4, cc = lane & 15;
#pragma unroll
  for (int hf = 0; hf < 2; ++hf) {
    __syncthreads();
    if (wc == hf) {
#pragma unroll
      for (int ni = 0; ni < 4; ++ni) {
        const float bias = bo[n0 + hf * 64 + ni * 16 + cc];
#pragma unroll
        for (int mi = 0; mi < 4; ++mi)
#pragma unroll
          for (int i = 0; i < 4; ++i)
            Cs[(wr * 64 + mi * 16 + r4 + i) * 68 + ni * 16 + cc] = acc[mi][ni][i] + bias;
      }
    }
    __syncthreads();
    const int rowp = tid >> 4, colg = tid & 15;
#pragma unroll
    for (int pass = 0; pass < 8; ++pass) {
      const int row = pass * 16 + rowp;
      const float4 v = *(const float4*)(Cs + row * 68 + colg * 4);
      *(float4*)(out0 + (size_t)(m0 + row) * V_ + n0 + hf * 64 + colg * 4) = v;
    }
  }
}

// ---------------- in-place log_softmax over V, one row per block ----------------

__global__ __launch_bounds__(256) void k_lsm(float* __restrict__ out0) {
  __shared__ float rm[256];
  __shared__ float rs[256];
  const int row = blockIdx.x, tid = threadIdx.x;
  float4* p = (float4*)(out0 + (size_t)row * V_);
  float m = -INFINITY, s = 0.f;
  for (int i = tid; i < V_ / 4; i += 256) {
    const float4 v = p[i];
    const float mx = fmaxf(fmaxf(v.x, v.y), fmaxf(v.z, v.w));
    if (mx > m) { s *= __expf(m - mx); m = mx; }
    s += __expf(v.x - m) + __expf(v.y - m) + __expf(v.z - m) + __expf(v.w - m);
  }
  rm[tid] = m; rs[tid] = s;
  __syncthreads();
  for (int off = 128; off > 0; off >>= 1) {
    if (tid < off) {
      const float m2 = rm[tid + off], s2 = rs[tid + off];
      const float M = fmaxf(rm[tid], m2);
      rs[tid] = rs[tid] * __expf(rm[tid] - M) + s2 * __expf(m2 - M);
      rm[tid] = M;
    }
    __syncthreads();
  }
  const float lse = rm[0] + __logf(rs[0]);
  for (int i = tid; i < V_ / 4; i += 256) {
    float4 v = p[i];
    v.x -= lse; v.y -= lse; v.z -= lse; v.w -= lse;
    p[i] = v;
  }
}

// ---------------- host ----------------

extern "C" void kernel_launch(void* const* d_in, const int* in_sizes, int n_in,
                              void* d_out, int out_size, void* d_ws, size_t ws_size,
                              hipStream_t stream) {
  (void)in_sizes; (void)n_in; (void)out_size; (void)ws_size;
  const float* enc  = (const float*)d_in[0];
  const float* ehs  = (const float*)d_in[1];
  const int*   tgt  = (const int*)d_in[2];
  const float* emb  = (const float*)d_in[3];
  const float* Wq   = (const float*)d_in[4];
  const float* bq   = (const float*)d_in[5];
  const float* Wk   = (const float*)d_in[6];
  const float* bk   = (const float*)d_in[7];
  const float* Wv   = (const float*)d_in[8];
  const float* bv   = (const float*)d_in[9];
  const float* W_ih = (const float*)d_in[10];
  const float* W_hh = (const float*)d_in[11];
  const float* b_ih = (const float*)d_in[12];
  const float* b_hh = (const float*)d_in[13];
  const float* Wo   = (const float*)d_in[14];
  const float* bo   = (const float*)d_in[15];

  float* out0 = (float*)d_out;                          // log_probs [2048, V]
  float* out1 = out0 + (size_t)B_ * T_ * V_;            // h_final [B*H]
  float* out2 = out1 + (size_t)B_ * H_;                 // attentions [B*T, S]

  // out0 doubles as scratch; k_logits overwrites all of it afterwards.
  float* kproj    = out0;                 // [0, 1,048,576)
  float* giemb    = out0 + 1048576;       // [.., 4,194,304)
  float* encprojT = out0 + 4194304;       // [1536][2048] -> [.., 7,340,032)
  float* h_st     = out0 + 7340032;       // 65 x 16384 -> [.., 8,404,992)
  float* partial  = out0 + 8404992;       // 64x32x8x64 -> [.., 9,453,568)
  __hip_bfloat16* enc_bf  = (__hip_bfloat16*)(out0 + 9453568);   // 1M bf16
  __hip_bfloat16* emb_bf  = (__hip_bfloat16*)(out0 + 9977856);   // 1M bf16
  __hip_bfloat16* wihc_bf = (__hip_bfloat16*)(out0 + 10502144);  // 0.75M bf16
  __hip_bfloat16* wq_bf   = (__hip_bfloat16*)(out0 + 10895360);  // 512x512 bf16
  __hip_bfloat16* whh_bf  = (__hip_bfloat16*)(out0 + 11026432);  // 1536x512 bf16

  __hip_bfloat16* Hall = (__hip_bfloat16*)d_ws;                   // 2 MB

  k_emb_gather<<<2048, 256, 0, stream>>>(tgt, emb, emb_bf);
  k_cvt_dense<<<1024, 256, 0, stream>>>(enc, enc_bf, 262144);
  k_cvt_wihc<<<1536, 128, 0, stream>>>(W_ih, wihc_bf);
  k_cvt_wqh<<<2048, 256, 0, stream>>>(Wq, W_hh, wq_bf, whh_bf);
  // sentinel-fill h_st[1..64] + partial (contiguous: [7356416, 9453568) = 524288 uint4)
  k_clear<<<2048, 256, 0, stream>>>((uint4*)(out0 + 7356416));
  k_init<<<64, 256, 0, stream>>>(ehs, h_st);

  // kproj[2048,512] = enc @ Wk^T + bk
  k_gemm_bf16<<<dim3(4, 16), 256, 0, stream>>>(enc_bf, 512, Wk, 512, bk, kproj, 512, 512);
  // giemb[2048,1536] = emb_all @ W_ih[:, :512]^T + b_ih
  k_gemm_bf16<<<dim3(12, 16), 256, 0, stream>>>(emb_bf, 512, W_ih, 1024, b_ih, giemb, 1536, 512);
  // encprojT[1536,2048] = W_ihc @ enc^T
  k_gemm_bf16<<<dim3(16, 12), 256, 0, stream>>>(wihc_bf, 512, enc, 512, nullptr, encprojT, 2048, 512);

  k_recur<<<256, 256, 0, stream>>>(wq_bf, whh_bf, bq, kproj, Wv, bv, encprojT,
                                   giemb, b_hh, h_st, partial, out2, Hall, out1);

  k_logits<<<4000, 256, 0, stream>>>(Hall, Wo, bo, out0);
  k_lsm<<<(B_ * T_), 256, 0, stream>>>(out0);
}